// Round 2
// baseline (971.273 us; speedup 1.0000x reference)
//
#include <hip/hip_runtime.h>

// FlowExp: v = flow/2^8; repeat 8x: v <- trilinear_pull(v, identity + v)
// Circular ("dft") bound + extrapolate=False. Inside the in-bounds test the
// floor index never needs a downward wrap, and the +1 corner wraps only when
// its weight is exactly 0 -> replace mod with clamp (value*0 == 0 either way).
// Interleaved (z,y,x,3) intermediate layout lets each (dz,dy) corner PAIR be
// one contiguous 24-byte load.

#define BB 2
#define DD 160
#define HH 192
#define WW 160

constexpr int PLANEHW = HH * WW;          // 30720
constexpr int PLANE   = DD * PLANEHW;     // 4,915,200
constexpr int NVOX    = BB * PLANE;       // 9,830,400

// IN_FMT : 0 = planar (B,3,D,H,W), each element scaled by `scale` (step 1: flow)
//          1 = packed interleaved (B,D,H,W,3)
// OUT_FMT: 0 = planar (final step), 1 = packed
template<int IN_FMT, int OUT_FMT>
__global__ __launch_bounds__(256) void flow_step(const float* __restrict__ vin,
                                                 float* __restrict__ vout,
                                                 float scale) {
    const int p = blockIdx.x * 256 + threadIdx.x;   // index within (H,W) plane
    const int x = p % WW;
    const int y = p / WW;
    const int z = blockIdx.y;
    const int b = blockIdx.z;
    const int t = (b * DD + z) * PLANEHW + p;       // voxel index

    // own-voxel displacement
    float vz, vy, vx;
    if (IN_FMT == 0) {
        const float* base = vin + b * 3 * PLANE + z * PLANEHW + p;
        vz = base[0] * scale;
        vy = base[PLANE] * scale;
        vx = base[2 * PLANE] * scale;
    } else {
        float c[3];
        __builtin_memcpy(c, vin + t * 3, 12);
        vz = c[0]; vy = c[1]; vx = c[2];
    }

    const float cz = (float)z + vz;
    const float cy = (float)y + vy;
    const float cx = (float)x + vx;

    float oz = 0.f, oy = 0.f, ox = 0.f;

    const bool inb = (cz >= 0.f) & (cz <= (float)(DD - 1)) &
                     (cy >= 0.f) & (cy <= (float)(HH - 1)) &
                     (cx >= 0.f) & (cx <= (float)(WW - 1));
    if (inb) {
        const float fz = floorf(cz), fy = floorf(cy), fx = floorf(cx);
        const float gz = cz - fz, gy = cy - fy, gx = cx - fx;
        const int iz = (int)fz, iy = (int)fy, ix = (int)fx;
        // wrap target always has weight 0 inside inb -> clamp is equivalent
        const int zi[2] = { iz, min(iz + 1, DD - 1) };
        const int yi[2] = { iy, min(iy + 1, HH - 1) };
        const float wzv[2] = { 1.f - gz, gz };
        const float wyv[2] = { 1.f - gy, gy };
        const float wx0 = 1.f - gx, wx1 = gx;

        #pragma unroll
        for (int dz = 0; dz < 2; ++dz) {
            #pragma unroll
            for (int dy = 0; dy < 2; ++dy) {
                const float wzy = wzv[dz] * wyv[dy];
                const float w0 = wzy * wx0, w1 = wzy * wx1;
                float c[6];   // corner (dx=0) channels 0..2, corner (dx=1) channels 3..5
                if (IN_FMT == 0) {
                    const int cell = (zi[dz] * HH + yi[dy]) * WW + ix;
                    const float* base = vin + b * 3 * PLANE + cell;
                    if ((cell < PLANE - 1) | (b < BB - 1)) {
                        // x-pair contiguous per channel plane; when ix==WW-1 the
                        // second element is next-row garbage but wx1 == 0.
                        float t0[2], t1[2], t2[2];
                        __builtin_memcpy(t0, base, 8);
                        __builtin_memcpy(t1, base + PLANE, 8);
                        __builtin_memcpy(t2, base + 2 * PLANE, 8);
                        c[0] = t0[0] * scale; c[3] = t0[1] * scale;
                        c[1] = t1[0] * scale; c[4] = t1[1] * scale;
                        c[2] = t2[0] * scale; c[5] = t2[1] * scale;
                    } else {   // very last voxel: avoid reading past the buffer
                        c[0] = base[0] * scale;
                        c[1] = base[PLANE] * scale;
                        c[2] = base[2 * PLANE] * scale;
                        c[3] = c[4] = c[5] = 0.f;
                    }
                } else {
                    const int q = (((b * DD + zi[dz]) * HH + yi[dy]) * WW + ix) * 3;
                    if (q <= 3 * NVOX - 6) {
                        __builtin_memcpy(c, vin + q, 24);   // dwordx4 + dwordx2
                    } else {   // only the single last cell can overrun
                        c[0] = vin[q]; c[1] = vin[q + 1]; c[2] = vin[q + 2];
                        c[3] = c[4] = c[5] = 0.f;
                    }
                }
                // accumulation order matches reference: corner dx=0 then dx=1
                oz += c[0] * w0; oy += c[1] * w0; ox += c[2] * w0;
                oz += c[3] * w1; oy += c[4] * w1; ox += c[5] * w1;
            }
        }
    }

    if (OUT_FMT == 0) {
        float* base = vout + b * 3 * PLANE + z * PLANEHW + p;
        base[0] = oz;
        base[PLANE] = oy;
        base[2 * PLANE] = ox;
    } else {
        float c[3] = { oz, oy, ox };
        __builtin_memcpy(vout + t * 3, c, 12);
    }
}

extern "C" void kernel_launch(void* const* d_in, const int* in_sizes, int n_in,
                              void* d_out, int out_size, void* d_ws, size_t ws_size,
                              hipStream_t stream) {
    const float* flow = (const float*)d_in[0];
    float* out = (float*)d_out;   // doubles as interleaved scratch for even steps
    float* wsA = (float*)d_ws;    // interleaved scratch (NVOX*3*4 = 118 MB)

    dim3 blk(256);
    dim3 grd(PLANEHW / 256, DD, BB);   // 120 x 160 x 2
    const float s = 1.f / 256.f;       // 1 / 2^NSTEPS

    flow_step<0, 1><<<grd, blk, 0, stream>>>(flow, wsA, s);
    flow_step<1, 1><<<grd, blk, 0, stream>>>(wsA, out, 1.f);
    flow_step<1, 1><<<grd, blk, 0, stream>>>(out, wsA, 1.f);
    flow_step<1, 1><<<grd, blk, 0, stream>>>(wsA, out, 1.f);
    flow_step<1, 1><<<grd, blk, 0, stream>>>(out, wsA, 1.f);
    flow_step<1, 1><<<grd, blk, 0, stream>>>(wsA, out, 1.f);
    flow_step<1, 1><<<grd, blk, 0, stream>>>(out, wsA, 1.f);
    flow_step<1, 0><<<grd, blk, 0, stream>>>(wsA, out, 1.f);
}

// Round 3
// 769.549 us; speedup vs baseline: 1.2621x; 1.2621x over previous
//
#include <hip/hip_runtime.h>

// FlowExp: v = flow/2^8; repeat 8x: v <- trilinear_pull(v, identity + v)
// Circular ("dft") bound + extrapolate=False. Inside the in-bounds region the
// floor index needs no downward wrap and the +1 corner wraps only with weight
// exactly 0 -> mod replaced by clamp. Out-of-bounds samples: clamp indices to
// valid memory, mask weights with inb (garbage*0 == 0), no divergence.
//
// Latency-bound op -> explicit phase structure: issue ALL gather loads before
// any consumption; 2 voxels/thread doubles loads-in-flight per wave.

#define BB 2
#define DD 160
#define HH 192
#define WW 160

constexpr int PLANEHW = HH * WW;          // 30720
constexpr int PLANE   = DD * PLANEHW;     // 4,915,200
constexpr int NVOX    = BB * PLANE;       // 9,830,400
constexpr int TPB     = 256;
constexpr int VPT     = 2;                // voxels per thread (wave-strided)

// IN_FMT : 0 = planar (B,3,D,H,W) scaled by `scale` (step 1 reads flow)
//          1 = packed interleaved (B,D,H,W,3)
// OUT_FMT: 0 = planar (final step), 1 = packed
template<int IN_FMT, int OUT_FMT>
__global__ __launch_bounds__(TPB) void flow_step(const float* __restrict__ vin,
                                                 float* __restrict__ vout,
                                                 float scale) {
    const int z = blockIdx.y;
    const int b = blockIdx.z;
    const int pbase = blockIdx.x * (TPB * VPT) + threadIdx.x;

    // ---- phase A: own-voxel displacement loads (coalesced) ----
    int pv[VPT], tv[VPT];
    float own[VPT][3];
    #pragma unroll
    for (int v = 0; v < VPT; ++v) {
        pv[v] = pbase + v * TPB;
        tv[v] = (b * DD + z) * PLANEHW + pv[v];
        if (IN_FMT == 0) {
            const float* base = vin + (b * 3 * PLANE + z * PLANEHW + pv[v]);
            own[v][0] = base[0] * scale;
            own[v][1] = base[PLANE] * scale;
            own[v][2] = base[2 * PLANE] * scale;
        } else {
            __builtin_memcpy(own[v], vin + (size_t)tv[v] * 3, 12);
        }
    }

    // ---- phase B: weights + clamped corner addresses (no memory ops) ----
    float wz[VPT][2], wy[VPT][2], wx[VPT][2];
    int abase[VPT][4];   // float-offset of the dx=0 corner per (dz,dy) pair
    int xoff[VPT];       // float-offset delta to the dx=1 corner (0 when w==0)
    #pragma unroll
    for (int v = 0; v < VPT; ++v) {
        const int x = pv[v] % WW;
        const int y = pv[v] / WW;
        const float cz = (float)z + own[v][0];
        const float cy = (float)y + own[v][1];
        const float cx = (float)x + own[v][2];
        const bool inb = (cz >= 0.f) & (cz <= (float)(DD - 1)) &
                         (cy >= 0.f) & (cy <= (float)(HH - 1)) &
                         (cx >= 0.f) & (cx <= (float)(WW - 1));
        const float inbf = inb ? 1.f : 0.f;
        const float fz = floorf(cz), fy = floorf(cy), fx = floorf(cx);
        const float gz = cz - fz, gy = cy - fy, gx = cx - fx;
        const int iz = (int)fz, iy = (int)fy, ix = (int)fx;
        // clamp keeps every address valid; weight-0 guarantees exactness in-bounds
        const int iz0 = min(max(iz, 0), DD - 1), iz1 = min(iz0 + 1, DD - 1);
        const int iy0 = min(max(iy, 0), HH - 1), iy1 = min(iy0 + 1, HH - 1);
        const int ix0 = min(max(ix, 0), WW - 1);
        xoff[v] = (ix0 < WW - 1) ? (IN_FMT == 0 ? 1 : 3) : 0;
        const float sfac = (IN_FMT == 0) ? scale : 1.f;   // fold input scale into weights
        wz[v][0] = (1.f - gz) * inbf * sfac;
        wz[v][1] = gz * inbf * sfac;
        wy[v][0] = 1.f - gy; wy[v][1] = gy;
        wx[v][0] = 1.f - gx; wx[v][1] = gx;
        #pragma unroll
        for (int dz = 0; dz < 2; ++dz)
            #pragma unroll
            for (int dy = 0; dy < 2; ++dy) {
                const int cell = ((dz ? iz1 : iz0) * HH + (dy ? iy1 : iy0)) * WW + ix0;
                abase[v][dz * 2 + dy] = (IN_FMT == 0) ? (b * 3 * PLANE + cell)
                                                      : ((b * PLANE + cell) * 3);
            }
    }

    // ---- phase C: issue ALL corner loads (nothing consumed yet) ----
    float c0[VPT][4][3], c1[VPT][4][3];
    #pragma unroll
    for (int v = 0; v < VPT; ++v)
        #pragma unroll
        for (int k = 0; k < 4; ++k) {
            if (IN_FMT == 0) {
                const float* bp = vin + abase[v][k];
                const int xo = xoff[v];
                c0[v][k][0] = bp[0];          c1[v][k][0] = bp[xo];
                c0[v][k][1] = bp[PLANE];      c1[v][k][1] = bp[PLANE + xo];
                c0[v][k][2] = bp[2 * PLANE];  c1[v][k][2] = bp[2 * PLANE + xo];
            } else {
                __builtin_memcpy(c0[v][k], vin + abase[v][k], 12);
                __builtin_memcpy(c1[v][k], vin + abase[v][k] + xoff[v], 12);
            }
        }

    // ---- phase D: accumulate (reference corner order) + store ----
    #pragma unroll
    for (int v = 0; v < VPT; ++v) {
        float oz = 0.f, oy = 0.f, ox = 0.f;
        #pragma unroll
        for (int dz = 0; dz < 2; ++dz)
            #pragma unroll
            for (int dy = 0; dy < 2; ++dy) {
                const int k = dz * 2 + dy;
                const float wzy = wz[v][dz] * wy[v][dy];
                const float w0 = wzy * wx[v][0], w1 = wzy * wx[v][1];
                oz += c0[v][k][0] * w0; oy += c0[v][k][1] * w0; ox += c0[v][k][2] * w0;
                oz += c1[v][k][0] * w1; oy += c1[v][k][1] * w1; ox += c1[v][k][2] * w1;
            }
        if (OUT_FMT == 0) {
            float* bp = vout + b * 3 * PLANE + z * PLANEHW + pv[v];
            bp[0] = oz; bp[PLANE] = oy; bp[2 * PLANE] = ox;
        } else {
            float cc[3] = { oz, oy, ox };
            __builtin_memcpy(vout + (size_t)tv[v] * 3, cc, 12);
        }
    }
}

extern "C" void kernel_launch(void* const* d_in, const int* in_sizes, int n_in,
                              void* d_out, int out_size, void* d_ws, size_t ws_size,
                              hipStream_t stream) {
    const float* flow = (const float*)d_in[0];
    float* out = (float*)d_out;   // doubles as interleaved scratch for even steps
    float* wsA = (float*)d_ws;    // interleaved scratch (NVOX*3*4 = 118 MB)

    dim3 blk(TPB);
    dim3 grd(PLANEHW / (TPB * VPT), DD, BB);   // 60 x 160 x 2
    const float s = 1.f / 256.f;               // 1 / 2^NSTEPS

    flow_step<0, 1><<<grd, blk, 0, stream>>>(flow, wsA, s);
    flow_step<1, 1><<<grd, blk, 0, stream>>>(wsA, out, 1.f);
    flow_step<1, 1><<<grd, blk, 0, stream>>>(out, wsA, 1.f);
    flow_step<1, 1><<<grd, blk, 0, stream>>>(wsA, out, 1.f);
    flow_step<1, 1><<<grd, blk, 0, stream>>>(out, wsA, 1.f);
    flow_step<1, 1><<<grd, blk, 0, stream>>>(wsA, out, 1.f);
    flow_step<1, 1><<<grd, blk, 0, stream>>>(out, wsA, 1.f);
    flow_step<1, 0><<<grd, blk, 0, stream>>>(wsA, out, 1.f);
}

// Round 4
// 594.802 us; speedup vs baseline: 1.6329x; 1.2938x over previous
//
#include <hip/hip_runtime.h>

// FlowExp: v = flow/2^8; repeat 8x: v <- trilinear_pull(v, identity + v)
// Key invariant: v_new is a convex combination of v_old samples, so
// ||v||_inf <= max|flow|/256 ~= 0.023 voxels for ALL steps. Every gather
// touches only the +-1 neighborhood -> LDS tile staging with halo 1 is exact.
// Staging is a coalesced streaming loop (independent loads -> real MLP);
// gathers run on the LDS pipe (SoA layout, lane stride 4B, conflict-free).

#define BB 2
#define DD 160
#define HH 192
#define WW 160

constexpr int PLANE = DD * HH * WW;   // 4,915,200

// IN_FMT : 0 = planar (B,3,D,H,W) scaled by `scale` (step 1 reads flow)
//          1 = packed interleaved (B,D,H,W,3)
// OUT_FMT: 0 = planar (final step), 1 = packed
template<int IN_FMT, int OUT_FMT, int TX, int TY, int TZ>
__global__ __launch_bounds__(256, 3) void flow_step(const float* __restrict__ vin,
                                                    float* __restrict__ vout,
                                                    float scale) {
    constexpr int LO = 1, HI = 1;
    constexpr int SX = TX + LO + HI, SY = TY + LO + HI, SZ = TZ + LO + HI;
    constexpr int NW = SX * SY * SZ;
    constexpr int NF = 3 * NW;
    __shared__ float lds[3][NW];

    const int x0 = blockIdx.x * TX;
    const int y0 = blockIdx.y * TY;
    constexpr int ZBLK = DD / TZ;
    const int b  = blockIdx.z / ZBLK;
    const int z0 = (blockIdx.z % ZBLK) * TZ;
    const int tid = threadIdx.x;

    // ---- stage tile+halo into LDS (SoA by channel), coalesced & batched ----
    constexpr int NITER = (NF + 255) / 256;
    #pragma unroll 8
    for (int k = 0; k < NITER; ++k) {
        const int i = min(tid + k * 256, NF - 1);   // branchless tail (dup write, same value)
        int ch, vox;
        if (IN_FMT == 0) { ch = i / NW; vox = i - ch * NW; }
        else             { vox = i / 3; ch = i - vox * 3; }
        const int szi = vox / (SY * SX);
        const int r   = vox - szi * (SY * SX);
        const int syi = r / SX;
        const int sxi = r - syi * SX;
        const int gz = min(max(z0 - LO + szi, 0), DD - 1);
        const int gy = min(max(y0 - LO + syi, 0), HH - 1);
        const int gx = min(max(x0 - LO + sxi, 0), WW - 1);
        float val;
        if (IN_FMT == 0)
            val = vin[(b * 3 + ch) * PLANE + (gz * HH + gy) * WW + gx] * scale;
        else
            val = vin[(((b * DD + gz) * HH + gy) * WW + gx) * 3 + ch];
        lds[ch][vox] = val;
    }
    __syncthreads();

    constexpr int TPP = TX * TY;
    constexpr int PZ  = 256 / TPP;
    const int tx = tid % TX;
    const int r2 = tid / TX;
    const int ty = r2 % TY;
    const int zo = r2 / TY;

    for (int zz = zo; zz < TZ; zz += PZ) {
        const int z = z0 + zz, y = y0 + ty, x = x0 + tx;
        const int so = ((zz + LO) * SY + (ty + LO)) * SX + (tx + LO);
        const float vz = lds[0][so], vy = lds[1][so], vx = lds[2][so];
        const float cz = (float)z + vz, cy = (float)y + vy, cx = (float)x + vx;
        const bool inb = (cz >= 0.f) & (cz <= (float)(DD - 1)) &
                         (cy >= 0.f) & (cy <= (float)(HH - 1)) &
                         (cx >= 0.f) & (cx <= (float)(WW - 1));
        const float inbf = inb ? 1.f : 0.f;
        const float fz = floorf(cz), fy = floorf(cy), fx = floorf(cx);
        const float gzf = cz - fz, gyf = cy - fy, gxf = cx - fx;
        const int iz = (int)fz, iy = (int)fy, ix = (int)fx;
        const int gz0 = min(max(iz, 0), DD - 1), gz1 = min(gz0 + 1, DD - 1);
        const int gy0 = min(max(iy, 0), HH - 1), gy1 = min(gy0 + 1, HH - 1);
        const int gx0 = min(max(ix, 0), WW - 1);
        const int s_z0 = gz0 - (z0 - LO), s_z1 = s_z0 + (gz1 - gz0);
        const int s_y0 = gy0 - (y0 - LO), s_y1 = s_y0 + (gy1 - gy0);
        const int s_x0 = gx0 - (x0 - LO);
        const bool ok = (s_z0 >= 0) & (s_z1 <= SZ - 1) &
                        (s_y0 >= 0) & (s_y1 <= SY - 1) &
                        (s_x0 >= 0) & (s_x0 <= SX - 2);
        const float wz0 = (1.f - gzf) * inbf, wz1 = gzf * inbf;
        const float wy0 = 1.f - gyf, wy1 = gyf;
        const float wx0 = 1.f - gxf, wx1 = gxf;

        float oz = 0.f, oy = 0.f, ox = 0.f;
        if (ok) {   // always true given ||v|| <= 0.023; fallback is safety net
            #pragma unroll
            for (int dz = 0; dz < 2; ++dz) {
                const int zrow = (dz ? s_z1 : s_z0) * SY;
                const float wzv = dz ? wz1 : wz0;
                #pragma unroll
                for (int dy = 0; dy < 2; ++dy) {
                    const int base = (zrow + (dy ? s_y1 : s_y0)) * SX + s_x0;
                    const float wzy = wzv * (dy ? wy1 : wy0);
                    const float w0 = wzy * wx0, w1 = wzy * wx1;
                    oz += lds[0][base] * w0;     oy += lds[1][base] * w0;     ox += lds[2][base] * w0;
                    oz += lds[0][base + 1] * w1; oy += lds[1][base + 1] * w1; ox += lds[2][base + 1] * w1;
                }
            }
        } else {    // rare/never: direct global gather with identical semantics
            const int zs[2] = { gz0, gz1 }, ys[2] = { gy0, gy1 };
            const int xs[2] = { gx0, min(gx0 + 1, WW - 1) };
            const float wzs[2] = { wz0, wz1 }, wys[2] = { wy0, wy1 }, wxs[2] = { wx0, wx1 };
            #pragma unroll
            for (int dz = 0; dz < 2; ++dz)
                #pragma unroll
                for (int dy = 0; dy < 2; ++dy)
                    #pragma unroll
                    for (int dx = 0; dx < 2; ++dx) {
                        float s0, s1, s2;
                        if (IN_FMT == 0) {
                            const float* bp = vin + b * 3 * PLANE + (zs[dz] * HH + ys[dy]) * WW + xs[dx];
                            s0 = bp[0] * scale; s1 = bp[PLANE] * scale; s2 = bp[2 * PLANE] * scale;
                        } else {
                            const float* bp = vin + (size_t)(((b * DD + zs[dz]) * HH + ys[dy]) * WW + xs[dx]) * 3;
                            s0 = bp[0]; s1 = bp[1]; s2 = bp[2];
                        }
                        const float w = wzs[dz] * wys[dy] * wxs[dx];
                        oz += s0 * w; oy += s1 * w; ox += s2 * w;
                    }
        }

        if (OUT_FMT == 0) {
            float* bp = vout + b * 3 * PLANE + (z * HH + y) * WW + x;
            bp[0] = oz; bp[PLANE] = oy; bp[2 * PLANE] = ox;
        } else {
            float* bp = vout + (size_t)(((b * DD + z) * HH + y) * WW + x) * 3;
            bp[0] = oz; bp[1] = oy; bp[2] = ox;
        }
    }
}

extern "C" void kernel_launch(void* const* d_in, const int* in_sizes, int n_in,
                              void* d_out, int out_size, void* d_ws, size_t ws_size,
                              hipStream_t stream) {
    const float* flow = (const float*)d_in[0];
    float* out = (float*)d_out;   // doubles as packed scratch for even steps
    float* wsA = (float*)d_ws;    // packed scratch (NVOX*3*4 = 118 MB)

    dim3 blk(256);
    dim3 grd(WW / 32, HH / 8, (DD / 8) * BB);   // 5 x 24 x 40
    const float s = 1.f / 256.f;                // 1 / 2^NSTEPS

    flow_step<0, 1, 32, 8, 8><<<grd, blk, 0, stream>>>(flow, wsA, s);
    flow_step<1, 1, 32, 8, 8><<<grd, blk, 0, stream>>>(wsA, out, 1.f);
    flow_step<1, 1, 32, 8, 8><<<grd, blk, 0, stream>>>(out, wsA, 1.f);
    flow_step<1, 1, 32, 8, 8><<<grd, blk, 0, stream>>>(wsA, out, 1.f);
    flow_step<1, 1, 32, 8, 8><<<grd, blk, 0, stream>>>(out, wsA, 1.f);
    flow_step<1, 1, 32, 8, 8><<<grd, blk, 0, stream>>>(wsA, out, 1.f);
    flow_step<1, 1, 32, 8, 8><<<grd, blk, 0, stream>>>(out, wsA, 1.f);
    flow_step<1, 0, 32, 8, 8><<<grd, blk, 0, stream>>>(wsA, out, 1.f);
}